// Round 5
// baseline (509.641 us; speedup 1.0000x reference)
//
#include <hip/hip_runtime.h>

#define N_NODES 50000
#define N_EDGES_MAX 800000
#define D_IN    128
#define D_OUT   64

#define BW      128                          // bucket width in nodes (pow2)
#define BSHIFT  7
#define NBKT    ((N_NODES + BW - 1) / BW)    // 391
#define BPAD    512                          // padded bucket-array size
#define PCHUNK  4096                         // edges per partition block
#define HCHUNK  8192                         // edges per hist block

// ---------------- Phase 1: support = x @ W  (f32 vector FMA) ----------------
#define NPB 16

__global__ __launch_bounds__(256) void gemm_xw(
    const float* __restrict__ x, const float* __restrict__ W,
    float* __restrict__ support) {
  __shared__ float Wlds[D_IN][D_OUT];   // 32 KiB
  __shared__ float xlds[NPB][D_IN];     //  8 KiB
  const int tid = threadIdx.x;
  const int node0 = blockIdx.x * NPB;

  const float4* W4 = (const float4*)W;
  float4* Wl4 = (float4*)Wlds;
#pragma unroll
  for (int i = 0; i < (D_IN * D_OUT / 4) / 256; ++i)
    Wl4[tid + i * 256] = W4[tid + i * 256];

  const float4* x4 = (const float4*)(x + (size_t)node0 * D_IN);
  float4* xl4 = (float4*)xlds;
#pragma unroll
  for (int i = 0; i < (NPB * D_IN / 4) / 256; ++i)
    xl4[tid + i * 256] = x4[tid + i * 256];

  __syncthreads();

  const int f = tid & 63;
  const int g = tid >> 6;
  float acc0 = 0.f, acc1 = 0.f, acc2 = 0.f, acc3 = 0.f;

#pragma unroll
  for (int k = 0; k < D_IN; k += 4) {
    const float w0 = Wlds[k + 0][f];
    const float w1 = Wlds[k + 1][f];
    const float w2 = Wlds[k + 2][f];
    const float w3 = Wlds[k + 3][f];
    const float4 xa = *(const float4*)&xlds[g * 4 + 0][k];
    const float4 xb = *(const float4*)&xlds[g * 4 + 1][k];
    const float4 xc = *(const float4*)&xlds[g * 4 + 2][k];
    const float4 xd = *(const float4*)&xlds[g * 4 + 3][k];
    acc0 += xa.x * w0 + xa.y * w1 + xa.z * w2 + xa.w * w3;
    acc1 += xb.x * w0 + xb.y * w1 + xb.z * w2 + xb.w * w3;
    acc2 += xc.x * w0 + xc.y * w1 + xc.z * w2 + xc.w * w3;
    acc3 += xd.x * w0 + xd.y * w1 + xd.z * w2 + xd.w * w3;
  }

  const int nbase = node0 + g * 4;
  support[(size_t)(nbase + 0) * D_OUT + f] = acc0;
  support[(size_t)(nbase + 1) * D_OUT + f] = acc1;
  support[(size_t)(nbase + 2) * D_OUT + f] = acc2;
  support[(size_t)(nbase + 3) * D_OUT + f] = acc3;
}

// ---------------- Phase 2a: per-bucket histogram (LDS-staged) ---------------
__global__ __launch_bounds__(256) void hist_bucket(
    const int* __restrict__ edst, int* __restrict__ gcnt, int n_edges) {
  __shared__ int lh[BPAD];
  const int t = threadIdx.x;
  for (int b = t; b < BPAD; b += 256) lh[b] = 0;
  __syncthreads();
  const int e0 = blockIdx.x * HCHUNK;
  const int e1 = min(e0 + HCHUNK, n_edges);
  for (int i = e0 + t; i < e1; i += 256)
    atomicAdd(&lh[edst[i] >> BSHIFT], 1);
  __syncthreads();
  for (int b = t; b < BPAD; b += 256) {
    const int c = lh[b];
    if (c) atomicAdd(&gcnt[b], c);
  }
}

// ---------------- Phase 2b: scan of 391 bucket counts (1 block) -------------
__global__ __launch_bounds__(BPAD) void scan_bucket(
    const int* __restrict__ gcnt, int* __restrict__ goff,
    int* __restrict__ gcur) {
  __shared__ int s[BPAD];
  const int t = threadIdx.x;
  const int c = gcnt[t];
  s[t] = c;
  __syncthreads();
  for (int off = 1; off < BPAD; off <<= 1) {
    const int o = (t >= off) ? s[t - off] : 0;
    __syncthreads();
    s[t] += o;
    __syncthreads();
  }
  const int ex = s[t] - c;   // exclusive prefix
  goff[t] = ex;              // goff[NBKT] == total (counts >= NBKT are 0)
  gcur[t] = ex;
}

// ---------------- Phase 2c: chunk-sorted bucket partition -------------------
// Each block chunk-sorts PCHUNK edges in LDS so global writes are contiguous
// per-bucket runs (coalesced) instead of random 8B writes.
__global__ __launch_bounds__(512) void partition(
    const int* __restrict__ esrc, const int* __restrict__ edst,
    const float* __restrict__ eval, int* __restrict__ gcur,
    int2* __restrict__ svp, int n_edges) {
  __shared__ int lh[BPAD], lscan[BPAD], lcur[BPAD], lbase[BPAD];
  __shared__ int2 stage[PCHUNK];        // 32 KiB
  const int t = threadIdx.x;
  const int e0 = blockIdx.x * PCHUNK;
  const int e1 = min(e0 + PCHUNK, n_edges);

  lh[t] = 0;
  __syncthreads();
  for (int i = e0 + t; i < e1; i += 512)
    atomicAdd(&lh[edst[i] >> BSHIFT], 1);
  __syncthreads();

  // inclusive Hillis-Steele over lh -> lscan
  const int v = lh[t];
  lscan[t] = v;
  __syncthreads();
  for (int off = 1; off < BPAD; off <<= 1) {
    const int o = (t >= off) ? lscan[t - off] : 0;
    __syncthreads();
    lscan[t] += o;
    __syncthreads();
  }
  const int ex = lscan[t] - v;   // own element only: no cross-thread read
  __syncthreads();
  lscan[t] = ex;                 // exclusive scan for binary search
  lcur[t] = ex;
  if (v > 0) lbase[t] = atomicAdd(&gcur[t], v);   // reserve global space
  __syncthreads();

  // place edges into chunk-sorted LDS staging
  for (int i = e0 + t; i < e1; i += 512) {
    const int d = edst[i];
    const int b = d >> BSHIFT;
    const int r = atomicAdd(&lcur[b], 1);
    stage[r] = make_int2((esrc[i] & 0xFFFF) | ((d & (BW - 1)) << 16),
                         __float_as_int(eval[i]));
  }
  __syncthreads();

  // copy out: consecutive LDS positions within a bucket run map to
  // consecutive global positions -> coalesced writes
  const int kn = e1 - e0;
  for (int p = t; p < kn; p += 512) {
    int lo = 0, hi = BPAD - 1;      // largest b with lscan[b] <= p
    while (lo < hi) {
      const int mid = (lo + hi + 1) >> 1;
      if (lscan[mid] <= p) lo = mid; else hi = mid - 1;
    }
    svp[lbase[lo] + (p - lscan[lo])] = stage[p];
  }
}

// ---------------- Phase 3: per-bucket LDS-accumulate + bias + relu ----------
// One block per bucket. accum[BW][64] f32 in LDS; lane = feature.
__global__ __launch_bounds__(512) void aggregate_lds(
    const float* __restrict__ support, const int* __restrict__ goff,
    const int2* __restrict__ svp, const float* __restrict__ bias,
    float* __restrict__ out) {
  __shared__ float accum[BW][D_OUT];    // 32 KiB
  const int t = threadIdx.x;
  const int f = t & 63;
  const int wid = t >> 6;               // 0..7
  const int bkt = blockIdx.x;
  const int nbase = bkt * BW;

  float4* a4 = (float4*)accum;
#pragma unroll
  for (int i = t; i < BW * D_OUT / 4; i += 512)
    a4[i] = make_float4(0.f, 0.f, 0.f, 0.f);
  __syncthreads();

  const int beg = goff[bkt];
  const int end = goff[bkt + 1];
  for (int base = beg + wid * 64; base < end; base += 512) {
    const int n = min(64, end - base);
    int pk = 0; float v = 0.f;
    if (f < n) {
      const int2 sv = svp[base + f];
      pk = sv.x; v = __int_as_float(sv.y);
    }
    for (int j = 0; j < n; ++j) {
      const int   pj = __shfl(pk, j);
      const float vj = __shfl(v, j);
      const int src = pj & 0xFFFF;
      const int dl  = pj >> 16;
      atomicAdd(&accum[dl][f], support[(size_t)src * D_OUT + f] * vj);
    }
  }
  __syncthreads();

  const float bf = bias[f];
  const int nrows = min(BW, N_NODES - nbase);
  for (int r = wid; r < nrows; r += 8)
    out[(size_t)(nbase + r) * D_OUT + f] = fmaxf(accum[r][f] + bf, 0.f);
}

// ---------------- Fallback (ws too small): atomic scatter -------------------
#define EPG 8
__global__ __launch_bounds__(256) void scatter_edges(
    const float* __restrict__ support, const int* __restrict__ esrc,
    const int* __restrict__ edst, const float* __restrict__ eval,
    float* __restrict__ out, int n_edges) {
  const int tid = threadIdx.x;
  const int f = tid & 63;
  const int grp = blockIdx.x * 4 + (tid >> 6);
  const int e0 = grp * EPG;
  int s[EPG], d[EPG];
  float v[EPG];
#pragma unroll
  for (int i = 0; i < EPG; ++i) {
    const int e = e0 + i;
    if (e < n_edges) { s[i] = esrc[e]; d[i] = edst[e]; v[i] = eval[e]; }
    else             { s[i] = 0; d[i] = 0; v[i] = 0.f; }
  }
  float m[EPG];
#pragma unroll
  for (int i = 0; i < EPG; ++i)
    m[i] = support[(size_t)s[i] * D_OUT + f] * v[i];
#pragma unroll
  for (int i = 0; i < EPG; ++i)
    if (e0 + i < n_edges) atomicAdd(&out[(size_t)d[i] * D_OUT + f], m[i]);
}

__global__ __launch_bounds__(256) void bias_relu(
    float* __restrict__ out, const float* __restrict__ b) {
  const int i = blockIdx.x * 256 + threadIdx.x;
  float4* o4 = (float4*)out;
  float4 v = o4[i];
  const int fb = (i * 4) & 63;
  const float4 bb = *(const float4*)&b[fb];
  v.x = fmaxf(v.x + bb.x, 0.f);
  v.y = fmaxf(v.y + bb.y, 0.f);
  v.z = fmaxf(v.z + bb.z, 0.f);
  v.w = fmaxf(v.w + bb.w, 0.f);
  o4[i] = v;
}

extern "C" void kernel_launch(void* const* d_in, const int* in_sizes, int n_in,
                              void* d_out, int out_size, void* d_ws, size_t ws_size,
                              hipStream_t stream) {
  const float* x    = (const float*)d_in[0];
  const int*   esrc = (const int*)  d_in[1];
  const int*   edst = (const int*)  d_in[2];
  const float* eval = (const float*)d_in[3];
  const float* W    = (const float*)d_in[4];
  const float* b    = (const float*)d_in[5];
  float* out = (float*)d_out;
  const int n_edges = in_sizes[1];

  // ---- workspace layout (256B aligned) ----
  size_t off = 0;
  auto alloc = [&](size_t bytes) {
    size_t o = off;
    off = (off + bytes + 255) & ~(size_t)255;
    return o;
  };
  char* ws = (char*)d_ws;
  const size_t sup_o  = alloc((size_t)N_NODES * D_OUT * sizeof(float));
  const size_t cnt_o  = alloc((size_t)BPAD * sizeof(int));
  const size_t offs_o = alloc((size_t)BPAD * sizeof(int));
  const size_t cur_o  = alloc((size_t)BPAD * sizeof(int));
  const size_t svp_o  = alloc((size_t)N_EDGES_MAX * sizeof(int2));
  const size_t req = off;

  float* support = (float*)(ws + sup_o);

  gemm_xw<<<N_NODES / NPB, 256, 0, stream>>>(x, W, support);

  if (ws_size >= req && n_edges <= N_EDGES_MAX) {
    int*  gcnt = (int*) (ws + cnt_o);
    int*  goff = (int*) (ws + offs_o);
    int*  gcur = (int*) (ws + cur_o);
    int2* svp  = (int2*)(ws + svp_o);

    hipMemsetAsync(gcnt, 0, (size_t)BPAD * sizeof(int), stream);

    hist_bucket<<<(n_edges + HCHUNK - 1) / HCHUNK, 256, 0, stream>>>(
        edst, gcnt, n_edges);
    scan_bucket<<<1, BPAD, 0, stream>>>(gcnt, goff, gcur);
    partition<<<(n_edges + PCHUNK - 1) / PCHUNK, 512, 0, stream>>>(
        esrc, edst, eval, gcur, svp, n_edges);
    aggregate_lds<<<NBKT, 512, 0, stream>>>(support, goff, svp, b, out);
  } else {
    // fallback: atomic scatter into zeroed out, then bias+relu
    hipMemsetAsync(d_out, 0, (size_t)N_NODES * D_OUT * sizeof(float), stream);
    const int groups = (n_edges + EPG - 1) / EPG;
    scatter_edges<<<(groups + 3) / 4, 256, 0, stream>>>(support, esrc, edst,
                                                        eval, out, n_edges);
    bias_relu<<<N_NODES * D_OUT / 4 / 256, 256, 0, stream>>>(out, b);
  }
}

// Round 6
// 197.833 us; speedup vs baseline: 2.5761x; 2.5761x over previous
//
#include <hip/hip_runtime.h>

#define N_NODES 50000
#define N_EDGES_MAX 800000
#define D_IN    128
#define D_OUT   64

#define BW      64                           // bucket width in nodes (pow2)
#define BSHIFT  6
#define NBKT    ((N_NODES + BW - 1) / BW)    // 782
#define BPAD    1024                         // padded bucket-array size (pow2)
#define PCHUNK  4096                         // edges per partition block
#define HCHUNK  8192                         // edges per hist block
#define ACH     2048                         // edges per aggregate LDS chunk

// ---------------- Phase 1: support = x @ W  (f32 vector FMA) ----------------
#define NPB 16

__global__ __launch_bounds__(256) void gemm_xw(
    const float* __restrict__ x, const float* __restrict__ W,
    float* __restrict__ support) {
  __shared__ float Wlds[D_IN][D_OUT];   // 32 KiB
  __shared__ float xlds[NPB][D_IN];     //  8 KiB
  const int tid = threadIdx.x;
  const int node0 = blockIdx.x * NPB;

  const float4* W4 = (const float4*)W;
  float4* Wl4 = (float4*)Wlds;
#pragma unroll
  for (int i = 0; i < (D_IN * D_OUT / 4) / 256; ++i)
    Wl4[tid + i * 256] = W4[tid + i * 256];

  const float4* x4 = (const float4*)(x + (size_t)node0 * D_IN);
  float4* xl4 = (float4*)xlds;
#pragma unroll
  for (int i = 0; i < (NPB * D_IN / 4) / 256; ++i)
    xl4[tid + i * 256] = x4[tid + i * 256];

  __syncthreads();

  const int f = tid & 63;
  const int g = tid >> 6;
  float acc0 = 0.f, acc1 = 0.f, acc2 = 0.f, acc3 = 0.f;

#pragma unroll
  for (int k = 0; k < D_IN; k += 4) {
    const float w0 = Wlds[k + 0][f];
    const float w1 = Wlds[k + 1][f];
    const float w2 = Wlds[k + 2][f];
    const float w3 = Wlds[k + 3][f];
    const float4 xa = *(const float4*)&xlds[g * 4 + 0][k];
    const float4 xb = *(const float4*)&xlds[g * 4 + 1][k];
    const float4 xc = *(const float4*)&xlds[g * 4 + 2][k];
    const float4 xd = *(const float4*)&xlds[g * 4 + 3][k];
    acc0 += xa.x * w0 + xa.y * w1 + xa.z * w2 + xa.w * w3;
    acc1 += xb.x * w0 + xb.y * w1 + xb.z * w2 + xb.w * w3;
    acc2 += xc.x * w0 + xc.y * w1 + xc.z * w2 + xc.w * w3;
    acc3 += xd.x * w0 + xd.y * w1 + xd.z * w2 + xd.w * w3;
  }

  const int nbase = node0 + g * 4;
  support[(size_t)(nbase + 0) * D_OUT + f] = acc0;
  support[(size_t)(nbase + 1) * D_OUT + f] = acc1;
  support[(size_t)(nbase + 2) * D_OUT + f] = acc2;
  support[(size_t)(nbase + 3) * D_OUT + f] = acc3;
}

// ---------------- Phase 2a: per-bucket histogram (LDS-staged) ---------------
__global__ __launch_bounds__(256) void hist_bucket(
    const int* __restrict__ edst, int* __restrict__ gcnt, int n_edges) {
  __shared__ int lh[BPAD];
  const int t = threadIdx.x;
  for (int b = t; b < BPAD; b += 256) lh[b] = 0;
  __syncthreads();
  const int e0 = blockIdx.x * HCHUNK;
  const int e1 = min(e0 + HCHUNK, n_edges);
  for (int i = e0 + t; i < e1; i += 256)
    atomicAdd(&lh[edst[i] >> BSHIFT], 1);
  __syncthreads();
  for (int b = t; b < BPAD; b += 256) {
    const int c = lh[b];
    if (c) atomicAdd(&gcnt[b], c);
  }
}

// ---------------- Phase 2b: scan of 1024 bucket counts (1 block) ------------
__global__ __launch_bounds__(1024) void scan_bucket(
    const int* __restrict__ gcnt, int* __restrict__ goff,
    int* __restrict__ gcur) {
  __shared__ int s[BPAD];
  const int t = threadIdx.x;
  const int c = gcnt[t];
  s[t] = c;
  __syncthreads();
  for (int off = 1; off < BPAD; off <<= 1) {
    const int o = (t >= off) ? s[t - off] : 0;
    __syncthreads();
    s[t] += o;
    __syncthreads();
  }
  const int ex = s[t] - c;   // exclusive prefix
  goff[t] = ex;              // goff[NBKT] == n_edges (counts >= NBKT are 0)
  gcur[t] = ex;
}

// ---------------- Phase 2c: chunk-sorted bucket partition -------------------
// Each block stages PCHUNK edges in registers, chunk-sorts them in LDS so
// global writes are contiguous per-bucket runs (coalesced).
__global__ __launch_bounds__(512) void partition(
    const int* __restrict__ esrc, const int* __restrict__ edst,
    const float* __restrict__ eval, int* __restrict__ gcur,
    int2* __restrict__ svp, int n_edges) {
  __shared__ int lh[BPAD], lscan[BPAD], lcur[BPAD], lbase[BPAD];
  __shared__ int tsum[512];
  __shared__ int2 stage[PCHUNK];        // 32 KiB (total ~50 KiB)
  const int t = threadIdx.x;
  const int e0 = blockIdx.x * PCHUNK;
  const int e1 = min(e0 + PCHUNK, n_edges);

  lh[t] = 0; lh[t + 512] = 0;
  __syncthreads();

  // stage up to 8 edges/thread in registers + local hist
  int  rs[8], rd[8];
  float rv[8];
#pragma unroll
  for (int k = 0; k < 8; ++k) {
    const int i = e0 + t + k * 512;
    if (i < e1) {
      rs[k] = esrc[i]; rd[k] = edst[i]; rv[k] = eval[i];
      atomicAdd(&lh[rd[k] >> BSHIFT], 1);
    } else {
      rs[k] = -1; rd[k] = 0; rv[k] = 0.f;
    }
  }
  __syncthreads();

  // exclusive scan of 1024 counters with 512 threads (2 per thread)
  const int a  = lh[2 * t];
  const int b2 = lh[2 * t + 1];
  tsum[t] = a + b2;
  __syncthreads();
  for (int off = 1; off < 512; off <<= 1) {
    const int o = (t >= off) ? tsum[t - off] : 0;
    __syncthreads();
    tsum[t] += o;
    __syncthreads();
  }
  const int ex = tsum[t] - (a + b2);
  lscan[2 * t]     = ex;
  lscan[2 * t + 1] = ex + a;
  lcur[2 * t]      = ex;
  lcur[2 * t + 1]  = ex + a;
  if (a)  lbase[2 * t]     = atomicAdd(&gcur[2 * t], a);
  if (b2) lbase[2 * t + 1] = atomicAdd(&gcur[2 * t + 1], b2);
  __syncthreads();

  // place from registers into chunk-sorted LDS staging
#pragma unroll
  for (int k = 0; k < 8; ++k) {
    if (rs[k] >= 0) {
      const int b = rd[k] >> BSHIFT;
      const int r = atomicAdd(&lcur[b], 1);
      stage[r] = make_int2((rs[k] & 0xFFFF) | ((rd[k] & (BW - 1)) << 16),
                           __float_as_int(rv[k]));
    }
  }
  __syncthreads();

  // copy out: consecutive LDS positions within a bucket run map to
  // consecutive global positions -> coalesced writes
  const int kn = e1 - e0;
  for (int p = t; p < kn; p += 512) {
    int lo = 0, hi = BPAD - 1;      // largest b with lscan[b] <= p
    while (lo < hi) {
      const int mid = (lo + hi + 1) >> 1;
      if (lscan[mid] <= p) lo = mid; else hi = mid - 1;
    }
    svp[lbase[lo] + (p - lscan[lo])] = stage[p];
  }
}

// ---------------- Phase 3: per-bucket sort + register aggregation -----------
// One block per 64-node bucket. Counting-sort the bucket's edges by dst-low
// in LDS, then each wave owns 8 dst rows and accumulates in REGISTERS
// (independent FMA chains, no atomics). Edge reads are wave-uniform LDS
// broadcasts; support gathers are 256B coalesced; one write per output row.
__global__ __launch_bounds__(512) void aggregate_bucket(
    const float* __restrict__ support, const int* __restrict__ goff,
    const int2* __restrict__ svp, const float* __restrict__ bias,
    float* __restrict__ out) {
  __shared__ int2 sorted[ACH];          // 16 KiB
  __shared__ int h[BW];
  __shared__ int ro[BW + 1];
  __shared__ int cur[BW];
  const int t = threadIdx.x;
  const int f = t & 63;
  const int wid = t >> 6;               // 0..7
  const int bkt = blockIdx.x;
  const int beg = goff[bkt];
  const int end = goff[bkt + 1];

  float acc[8];
#pragma unroll
  for (int k = 0; k < 8; ++k) acc[k] = 0.f;

  for (int cbeg = beg; cbeg < end; cbeg += ACH) {
    const int cn = min(ACH, end - cbeg);
    if (t < BW) h[t] = 0;
    __syncthreads();

    // stage up to 4 edges/thread in registers + hist (static indexing)
    int2 m0 = make_int2(0, 0), m1 = m0, m2 = m0, m3 = m0;
    const int i0 = t, i1 = t + 512, i2 = t + 1024, i3 = t + 1536;
    if (i0 < cn) { m0 = svp[cbeg + i0]; atomicAdd(&h[m0.x >> 16], 1); }
    if (i1 < cn) { m1 = svp[cbeg + i1]; atomicAdd(&h[m1.x >> 16], 1); }
    if (i2 < cn) { m2 = svp[cbeg + i2]; atomicAdd(&h[m2.x >> 16], 1); }
    if (i3 < cn) { m3 = svp[cbeg + i3]; atomicAdd(&h[m3.x >> 16], 1); }
    __syncthreads();

    // wave 0: shfl-scan of 64 counters (no intra-wave barrier needed)
    if (wid == 0) {
      const int c = h[f];
      int v = c;
#pragma unroll
      for (int off = 1; off < 64; off <<= 1) {
        const int u = __shfl_up(v, off);
        if (f >= off) v += u;
      }
      const int exo = v - c;
      ro[f] = exo;
      cur[f] = exo;
      if (f == 63) ro[64] = cn;
    }
    __syncthreads();

    // place into dst-sorted LDS
    if (i0 < cn) { const int r = atomicAdd(&cur[m0.x >> 16], 1); sorted[r] = m0; }
    if (i1 < cn) { const int r = atomicAdd(&cur[m1.x >> 16], 1); sorted[r] = m1; }
    if (i2 < cn) { const int r = atomicAdd(&cur[m2.x >> 16], 1); sorted[r] = m2; }
    if (i3 < cn) { const int r = atomicAdd(&cur[m3.x >> 16], 1); sorted[r] = m3; }
    __syncthreads();

    // register aggregation: wave wid owns rows wid*8 .. wid*8+7
#pragma unroll
    for (int k = 0; k < 8; ++k) {
      const int row = wid * 8 + k;
      const int rb = ro[row];
      const int re = ro[row + 1];
      for (int j = rb; j < re; ++j) {
        const int2 e = sorted[j];                  // wave-uniform broadcast
        acc[k] += support[(size_t)(e.x & 0xFFFF) * D_OUT + f] *
                  __int_as_float(e.y);
      }
    }
    __syncthreads();
  }

  const float bf = bias[f];
  const int nbase = bkt * BW;
#pragma unroll
  for (int k = 0; k < 8; ++k) {
    const int node = nbase + wid * 8 + k;
    if (node < N_NODES)
      out[(size_t)node * D_OUT + f] = fmaxf(acc[k] + bf, 0.f);
  }
}

// ---------------- Fallback (ws too small): atomic scatter -------------------
#define EPG 8
__global__ __launch_bounds__(256) void scatter_edges(
    const float* __restrict__ support, const int* __restrict__ esrc,
    const int* __restrict__ edst, const float* __restrict__ eval,
    float* __restrict__ out, int n_edges) {
  const int tid = threadIdx.x;
  const int f = tid & 63;
  const int grp = blockIdx.x * 4 + (tid >> 6);
  const int e0 = grp * EPG;
  int s[EPG], d[EPG];
  float v[EPG];
#pragma unroll
  for (int i = 0; i < EPG; ++i) {
    const int e = e0 + i;
    if (e < n_edges) { s[i] = esrc[e]; d[i] = edst[e]; v[i] = eval[e]; }
    else             { s[i] = 0; d[i] = 0; v[i] = 0.f; }
  }
  float m[EPG];
#pragma unroll
  for (int i = 0; i < EPG; ++i)
    m[i] = support[(size_t)s[i] * D_OUT + f] * v[i];
#pragma unroll
  for (int i = 0; i < EPG; ++i)
    if (e0 + i < n_edges) atomicAdd(&out[(size_t)d[i] * D_OUT + f], m[i]);
}

__global__ __launch_bounds__(256) void bias_relu(
    float* __restrict__ out, const float* __restrict__ b) {
  const int i = blockIdx.x * 256 + threadIdx.x;
  float4* o4 = (float4*)out;
  float4 v = o4[i];
  const int fb = (i * 4) & 63;
  const float4 bb = *(const float4*)&b[fb];
  v.x = fmaxf(v.x + bb.x, 0.f);
  v.y = fmaxf(v.y + bb.y, 0.f);
  v.z = fmaxf(v.z + bb.z, 0.f);
  v.w = fmaxf(v.w + bb.w, 0.f);
  o4[i] = v;
}

extern "C" void kernel_launch(void* const* d_in, const int* in_sizes, int n_in,
                              void* d_out, int out_size, void* d_ws, size_t ws_size,
                              hipStream_t stream) {
  const float* x    = (const float*)d_in[0];
  const int*   esrc = (const int*)  d_in[1];
  const int*   edst = (const int*)  d_in[2];
  const float* eval = (const float*)d_in[3];
  const float* W    = (const float*)d_in[4];
  const float* b    = (const float*)d_in[5];
  float* out = (float*)d_out;
  const int n_edges = in_sizes[1];

  // ---- workspace layout (256B aligned) ----
  size_t off = 0;
  auto alloc = [&](size_t bytes) {
    size_t o = off;
    off = (off + bytes + 255) & ~(size_t)255;
    return o;
  };
  char* ws = (char*)d_ws;
  const size_t sup_o  = alloc((size_t)N_NODES * D_OUT * sizeof(float));
  const size_t cnt_o  = alloc((size_t)BPAD * sizeof(int));
  const size_t offs_o = alloc((size_t)BPAD * sizeof(int));
  const size_t cur_o  = alloc((size_t)BPAD * sizeof(int));
  const size_t svp_o  = alloc((size_t)N_EDGES_MAX * sizeof(int2));
  const size_t req = off;

  float* support = (float*)(ws + sup_o);

  gemm_xw<<<N_NODES / NPB, 256, 0, stream>>>(x, W, support);

  if (ws_size >= req && n_edges <= N_EDGES_MAX) {
    int*  gcnt = (int*) (ws + cnt_o);
    int*  goff = (int*) (ws + offs_o);
    int*  gcur = (int*) (ws + cur_o);
    int2* svp  = (int2*)(ws + svp_o);

    hipMemsetAsync(gcnt, 0, (size_t)BPAD * sizeof(int), stream);

    hist_bucket<<<(n_edges + HCHUNK - 1) / HCHUNK, 256, 0, stream>>>(
        edst, gcnt, n_edges);
    scan_bucket<<<1, BPAD, 0, stream>>>(gcnt, goff, gcur);
    partition<<<(n_edges + PCHUNK - 1) / PCHUNK, 512, 0, stream>>>(
        esrc, edst, eval, gcur, svp, n_edges);
    aggregate_bucket<<<NBKT, 512, 0, stream>>>(support, goff, svp, b, out);
  } else {
    // fallback: atomic scatter into zeroed out, then bias+relu
    hipMemsetAsync(d_out, 0, (size_t)N_NODES * D_OUT * sizeof(float), stream);
    const int groups = (n_edges + EPG - 1) / EPG;
    scatter_edges<<<(groups + 3) / 4, 256, 0, stream>>>(support, esrc, edst,
                                                        eval, out, n_edges);
    bias_relu<<<N_NODES * D_OUT / 4 / 256, 256, 0, stream>>>(out, b);
  }
}